// Round 1
// baseline (913.363 us; speedup 1.0000x reference)
//
#include <hip/hip_runtime.h>
#include <math.h>

#define B_ 128
#define J_ 32
#define I_ 1152
#define N_ 16
#define TI 16          // i per stage step
#define STEPS 4        // stage steps per block -> 64 i per block
#define NT (I_/(TI*STEPS))   // 18 blocks per example in i

// ws layout (float offsets)
#define OFF_W   0
#define OFF_S1  65536
#define OFF_S2  131072
#define OFF_S0  196608
#define OFF_SC0 262144
#define OFF_SC1 266240
#define OFF_M0  270336
#define OFF_M1  274432

// Zero the accumulated buffers (s1,s2,scores0,scores1 contiguous) + entropy out.
__global__ void zero_kernel(float* __restrict__ ws, float* __restrict__ ent) {
    int idx = blockIdx.x * 256 + threadIdx.x;
    const int n = 2 * 65536 + 2 * 4096; // 139264
    for (int k = idx; k < n; k += gridDim.x * 256) ws[OFF_S1 + k] = 0.f;
    if (idx < B_ * 3) ent[idx] = 0.f;
}

// s0[b,j,n] = sum_i U[b,j,i,n]. One block per (b,j), contiguous coalesced float4.
__global__ void sum_kernel(const float* __restrict__ U, float* __restrict__ s0) {
    int bj  = blockIdx.x;
    int tid = threadIdx.x;           // 256
    int nc  = tid & 3;
    int ip  = tid >> 2;              // 0..63
    const float4* base = (const float4*)(U + (size_t)bj * I_ * N_);
    float4 acc = make_float4(0.f, 0.f, 0.f, 0.f);
    for (int i = ip; i < I_; i += 64) {
        float4 u = base[i * 4 + nc];
        acc.x += u.x; acc.y += u.y; acc.z += u.z; acc.w += u.w;
    }
    __shared__ float4 lds[256];
    lds[nc * 64 + ip] = acc;
    __syncthreads();
    for (int s = 32; s >= 1; s >>= 1) {
        if (ip < s) {
            float4 a = lds[nc * 64 + ip], b = lds[nc * 64 + ip + s];
            a.x += b.x; a.y += b.y; a.z += b.z; a.w += b.w;
            lds[nc * 64 + ip] = a;
        }
        __syncthreads();
    }
    if (ip == 0) ((float4*)s0)[bj * 4 + nc] = lds[nc * 64];
}

// squash + w update. mode 0=init (w=v, ent0=log32, scale=1/32), 1=update (w+=v), 2=final (out=v)
__global__ void vupdate_kernel(const float* __restrict__ s, const float* __restrict__ bias,
                               float* __restrict__ w, float* __restrict__ out_v,
                               float* __restrict__ ent, float scale, int mode) {
    int b = blockIdx.x;
    int tid = threadIdx.x;           // 512: j=tid>>4, n=tid&15
    int j = tid >> 4, n = tid & 15;
    int idx = (b * J_ + j) * N_ + n;
    float sv = s[idx] * scale;
    float rs = sv;
    for (int k = 8; k; k >>= 1) rs += __shfl_xor(rs, k);
    float sb = (rs == 0.f) ? 0.f : sv + bias[j * N_ + n];
    float sq = sb * sb;
    for (int k = 8; k; k >>= 1) sq += __shfl_xor(sq, k);
    float v = (sq / (1.f + sq)) * (sb / sqrtf(sq + 1e-8f));
    if (mode == 0) {
        w[idx] = v;
        if (tid == 0) ent[b * 3] = logf(32.f);
    } else if (mode == 1) {
        w[idx] += v;
    } else {
        out_v[idx] = v;
    }
}

// Streaming pass, LDS-staged for coalesced HBM access.
// mode 0: scores[b,j] += sum_i p ;  mode 1: s[b,j,n] += sum_i p*U, entropy accum.
// rev=1 reverses the block->chunk mapping so consecutive passes traverse U in
// opposite directions (serpentine) -> tail of previous pass is L3-resident.
// Staging is register-prefetched (async-stage split): next step's loads are in
// flight during the current step's compute, single LDS buffer (occupancy kept).
__global__ __launch_bounds__(256) void pass_kernel(
        const float* __restrict__ U, const float* __restrict__ w,
        const int* __restrict__ mask, float* __restrict__ scores,
        float* __restrict__ s_out, float* __restrict__ ent,
        int ent_idx, int mode, int rev) {
    // staging buffer: 32 j-planes x (TI*4 + 1 pad) float4  -> bank-balanced both phases
    __shared__ float4 lds[J_ * (TI * 4 + 1)];   // 33,280 B
    __shared__ float le[256];

    int bid = rev ? (gridDim.x - 1 - blockIdx.x) : blockIdx.x;
    int b = bid / NT, chunk = bid % NT;
    int i0 = chunk * (TI * STEPS);
    int tid = threadIdx.x;           // 256
    int j = tid & 31, sub = tid >> 5;

    const float4* wp = (const float4*)(w + (b * J_ + j) * N_);
    float4 w0 = wp[0], w1 = wp[1], w2 = wp[2], w3 = wp[3];
    bool active = mask ? (mask[b * J_ + j] != 0) : true;

    float acc_sc = 0.f, acc_ent = 0.f;
    float4 a0 = make_float4(0,0,0,0), a1 = a0, a2 = a0, a3 = a0;

    const float4* Ub = (const float4*)U;

    // prologue: prefetch step 0 into registers
    float4 pre[8];
    #pragma unroll
    for (int r = 0; r < 8; ++r) {
        int f  = tid + 256 * r;      // 0..2047
        int js = f >> 6;             // j-plane (64 float4 per j)
        int q  = f & 63;             // i_loc*4 + g
        pre[r] = Ub[((size_t)(b * J_ + js) * I_ + i0) * 4 + q];
    }

    for (int st = 0; st < STEPS; ++st) {
        // ---- drain prefetch into LDS
        #pragma unroll
        for (int r = 0; r < 8; ++r) {
            int f  = tid + 256 * r;
            lds[(f >> 6) * 65 + (f & 63)] = pre[r];
        }
        __syncthreads();
        // ---- issue next step's global loads (in flight during compute)
        if (st + 1 < STEPS) {
            int ib = i0 + (st + 1) * TI;
            #pragma unroll
            for (int r = 0; r < 8; ++r) {
                int f  = tid + 256 * r;
                pre[r] = Ub[((size_t)(b * J_ + (f >> 6)) * I_ + ib) * 4 + (f & 63)];
            }
        }
        // ---- compute from LDS
        #pragma unroll
        for (int t2 = 0; t2 < 2; ++t2) {
            int ii = sub + t2 * 8;       // 0..15
            const float4* up = &lds[j * 65 + ii * 4];
            float4 u0 = up[0], u1 = up[1], u2 = up[2], u3 = up[3];
            float y = u0.x * w0.x + u0.y * w0.y + u0.z * w0.z + u0.w * w0.w
                    + u1.x * w1.x + u1.y * w1.y + u1.z * w1.z + u1.w * w1.w
                    + u2.x * w2.x + u2.y * w2.y + u2.z * w2.z + u2.w * w2.w
                    + u3.x * w3.x + u3.y * w3.y + u3.z * w3.z + u3.w * w3.w;
            // |y| <= |u||w| ~ 12 max -> exp safe in f32 without max-subtraction
            float e = active ? __expf(y) : 0.f;
            float Z = e;
            for (int k = 16; k; k >>= 1) Z += __shfl_xor(Z, k);
            float p = e / Z;
            if (mode == 0) {
                acc_sc += p;
            } else {
                a0.x += p * u0.x; a0.y += p * u0.y; a0.z += p * u0.z; a0.w += p * u0.w;
                a1.x += p * u1.x; a1.y += p * u1.y; a1.z += p * u1.z; a1.w += p * u1.w;
                a2.x += p * u2.x; a2.y += p * u2.y; a2.z += p * u2.z; a2.w += p * u2.w;
                a3.x += p * u3.x; a3.y += p * u3.y; a3.z += p * u3.z; a3.w += p * u3.w;
                acc_ent += p * (y - __logf(Z));   // p*log(p), exact 0 for p==0
            }
        }
        __syncthreads();   // LDS reused next step
    }

    if (mode == 0) {
        le[tid] = acc_sc;
        __syncthreads();
        if (tid < 32) {
            float t = 0.f;
            for (int s = 0; s < 8; s++) t += le[s * 32 + tid];
            atomicAdd(&scores[b * J_ + tid], t);
        }
    } else {
        float* ls = (float*)lds;          // reuse staging buffer (8320 floats >= 4096)
        float* myl = ls + tid * 16;
        ((float4*)myl)[0] = a0; ((float4*)myl)[1] = a1;
        ((float4*)myl)[2] = a2; ((float4*)myl)[3] = a3;
        le[tid] = acc_ent;
        __syncthreads();
        for (int idx = tid; idx < 512; idx += 256) {
            int jj = idx >> 4, nn = idx & 15;
            float t = 0.f;
            for (int s = 0; s < 8; s++) t += ls[(s * 32 + jj) * 16 + nn];
            atomicAdd(&s_out[(b * J_ + jj) * N_ + nn], t);
        }
        for (int s = 128; s >= 1; s >>= 1) {
            if (tid < s) le[tid] += le[tid + s];
            __syncthreads();
        }
        if (tid == 0) atomicAdd(&ent[b * 3 + ent_idx], -le[0] * (1.f / (float)I_));
    }
}

// Stable top-K over 32 scores per example (tie-break: lower index, as jax.lax.top_k).
__global__ void topk_kernel(const float* __restrict__ scores, int* __restrict__ mask, int K) {
    int b = blockIdx.x;
    int tid = threadIdx.x;   // 64, first 32 active
    __shared__ float ls[32];
    if (tid < 32) ls[tid] = scores[b * 32 + tid];
    __syncthreads();
    if (tid < 32) {
        float sv = ls[tid];
        int rank = 0;
        for (int jj = 0; jj < 32; jj++) {
            float o = ls[jj];
            rank += (o > sv) || (o == sv && jj < tid);
        }
        mask[b * 32 + tid] = (rank < K) ? 1 : 0;
    }
}

extern "C" void kernel_launch(void* const* d_in, const int* in_sizes, int n_in,
                              void* d_out, int out_size, void* d_ws, size_t ws_size,
                              hipStream_t stream) {
    const float* U    = (const float*)d_in[0];
    const float* bias = (const float*)d_in[1];
    float* ws  = (float*)d_ws;
    float* out = (float*)d_out;
    float* ent = out + B_ * J_ * N_;

    float* w   = ws + OFF_W;
    float* s0  = ws + OFF_S0;
    float* s1  = ws + OFF_S1;
    float* s2  = ws + OFF_S2;
    float* sc0 = ws + OFF_SC0;
    float* sc1 = ws + OFF_SC1;
    int*   m0  = (int*)(ws + OFF_M0);
    int*   m1  = (int*)(ws + OFF_M1);

    zero_kernel<<<544, 256, 0, stream>>>(ws, ent);

    // iter 0: c uniform 1/32   (U traversal: ascending)
    sum_kernel<<<B_ * J_, 256, 0, stream>>>(U, s0);
    vupdate_kernel<<<B_, 512, 0, stream>>>(s0, bias, w, nullptr, ent, 1.f / 32.f, 0);

    // scores for top-20 mask   (descending -> reuse L3 tail of sum pass)
    pass_kernel<<<B_ * NT, 256, 0, stream>>>(U, w, nullptr, sc0, nullptr, nullptr, 0, 0, 1);
    topk_kernel<<<B_, 64, 0, stream>>>(sc0, m0, 20);

    // iter 1: masked softmax -> s1, entropy1; w2 = w1 + v1   (ascending)
    pass_kernel<<<B_ * NT, 256, 0, stream>>>(U, w, m0, nullptr, s1, ent, 1, 1, 0);
    vupdate_kernel<<<B_, 512, 0, stream>>>(s1, bias, w, nullptr, ent, 1.f, 1);

    // scores for top-12 mask   (descending)
    pass_kernel<<<B_ * NT, 256, 0, stream>>>(U, w, m0, sc1, nullptr, nullptr, 0, 0, 1);
    topk_kernel<<<B_, 64, 0, stream>>>(sc1, m1, 12);

    // iter 2: masked softmax -> s2, entropy2; v2 -> output   (ascending)
    pass_kernel<<<B_ * NT, 256, 0, stream>>>(U, w, m1, nullptr, s2, ent, 2, 1, 0);
    vupdate_kernel<<<B_, 512, 0, stream>>>(s2, bias, nullptr, out, ent, 1.f, 2);
}

// Round 2
// 603.592 us; speedup vs baseline: 1.5132x; 1.5132x over previous
//
#include <hip/hip_runtime.h>
#include <math.h>

#define B_ 128
#define J_ 32
#define I_ 1152
#define N_ 16
#define TI 16          // i per stage step
#define STEPS 4        // stage steps per block -> 64 i per block
#define NT (I_/(TI*STEPS))   // 18 blocks per example in i

// ws layout (float offsets)
#define OFF_W   0
#define OFF_S1  65536
#define OFF_S2  131072
#define OFF_S0  196608
#define OFF_SC0 262144
#define OFF_SC1 266240
#define OFF_M0  270336
#define OFF_M1  274432

// Zero the accumulated buffers (s1,s2,scores0,scores1 contiguous) + entropy out.
__global__ void zero_kernel(float* __restrict__ ws, float* __restrict__ ent) {
    int idx = blockIdx.x * 256 + threadIdx.x;
    const int n = 2 * 65536 + 2 * 4096; // 139264
    for (int k = idx; k < n; k += gridDim.x * 256) ws[OFF_S1 + k] = 0.f;
    if (idx < B_ * 3) ent[idx] = 0.f;
}

// s0[b,j,n] = sum_i U[b,j,i,n]. One block per (b,j), contiguous coalesced float4.
__global__ void sum_kernel(const float* __restrict__ U, float* __restrict__ s0) {
    int bj  = blockIdx.x;
    int tid = threadIdx.x;           // 256
    int nc  = tid & 3;
    int ip  = tid >> 2;              // 0..63
    const float4* base = (const float4*)(U + (size_t)bj * I_ * N_);
    float4 acc = make_float4(0.f, 0.f, 0.f, 0.f);
    for (int i = ip; i < I_; i += 64) {
        float4 u = base[i * 4 + nc];
        acc.x += u.x; acc.y += u.y; acc.z += u.z; acc.w += u.w;
    }
    __shared__ float4 lds[256];
    lds[nc * 64 + ip] = acc;
    __syncthreads();
    for (int s = 32; s >= 1; s >>= 1) {
        if (ip < s) {
            float4 a = lds[nc * 64 + ip], b = lds[nc * 64 + ip + s];
            a.x += b.x; a.y += b.y; a.z += b.z; a.w += b.w;
            lds[nc * 64 + ip] = a;
        }
        __syncthreads();
    }
    if (ip == 0) ((float4*)s0)[bj * 4 + nc] = lds[nc * 64];
}

// squash + w update. mode 0=init (w=v, ent0=log32, scale=1/32), 1=update (w+=v), 2=final (out=v)
__global__ void vupdate_kernel(const float* __restrict__ s, const float* __restrict__ bias,
                               float* __restrict__ w, float* __restrict__ out_v,
                               float* __restrict__ ent, float scale, int mode) {
    int b = blockIdx.x;
    int tid = threadIdx.x;           // 512: j=tid>>4, n=tid&15
    int j = tid >> 4, n = tid & 15;
    int idx = (b * J_ + j) * N_ + n;
    float sv = s[idx] * scale;
    float rs = sv;
    for (int k = 8; k; k >>= 1) rs += __shfl_xor(rs, k);
    float sb = (rs == 0.f) ? 0.f : sv + bias[j * N_ + n];
    float sq = sb * sb;
    for (int k = 8; k; k >>= 1) sq += __shfl_xor(sq, k);
    float v = (sq / (1.f + sq)) * (sb / sqrtf(sq + 1e-8f));
    if (mode == 0) {
        w[idx] = v;
        if (tid == 0) ent[b * 3] = logf(32.f);
    } else if (mode == 1) {
        w[idx] += v;
    } else {
        out_v[idx] = v;
    }
}

// Streaming pass, LDS-staged for coalesced HBM access.
// mode 0: scores[b,j] += sum_i p ;  mode 1: s[b,j,n] += sum_i p*U, entropy accum.
// rev=1 reverses the block->chunk mapping so consecutive passes traverse U in
// opposite directions (serpentine) -> tail of previous pass is L3-resident.
__global__ __launch_bounds__(256) void pass_kernel(
        const float* __restrict__ U, const float* __restrict__ w,
        const int* __restrict__ mask, float* __restrict__ scores,
        float* __restrict__ s_out, float* __restrict__ ent,
        int ent_idx, int mode, int rev) {
    // staging buffer: 32 j-planes x (TI*4 + 1 pad) float4  -> bank-balanced both phases
    __shared__ float4 lds[J_ * (TI * 4 + 1)];   // 33,280 B
    __shared__ float le[256];

    int bid = rev ? (gridDim.x - 1 - blockIdx.x) : blockIdx.x;
    int b = bid / NT, chunk = bid % NT;
    int i0 = chunk * (TI * STEPS);
    int tid = threadIdx.x;           // 256
    int j = tid & 31, sub = tid >> 5;

    const float4* wp = (const float4*)(w + (b * J_ + j) * N_);
    float4 w0 = wp[0], w1 = wp[1], w2 = wp[2], w3 = wp[3];
    bool active = mask ? (mask[b * J_ + j] != 0) : true;

    float acc_sc = 0.f, acc_ent = 0.f;
    float4 a0 = make_float4(0,0,0,0), a1 = a0, a2 = a0, a3 = a0;

    const float4* Ub = (const float4*)U;

    for (int st = 0; st < STEPS; ++st) {
        int ibase = i0 + st * TI;
        // ---- stage: coalesced global -> LDS (each wave reads contiguous 1KB/instr)
        #pragma unroll
        for (int r = 0; r < 8; ++r) {
            int f  = tid + 256 * r;      // 0..2047
            int js = f >> 6;             // j-plane (64 float4 per j)
            int q  = f & 63;             // i_loc*4 + g
            lds[js * 65 + q] = Ub[((size_t)(b * J_ + js) * I_ + ibase) * 4 + q];
        }
        __syncthreads();
        // ---- compute from LDS
        #pragma unroll
        for (int t2 = 0; t2 < 2; ++t2) {
            int ii = sub + t2 * 8;       // 0..15
            const float4* up = &lds[j * 65 + ii * 4];
            float4 u0 = up[0], u1 = up[1], u2 = up[2], u3 = up[3];
            float y = u0.x * w0.x + u0.y * w0.y + u0.z * w0.z + u0.w * w0.w
                    + u1.x * w1.x + u1.y * w1.y + u1.z * w1.z + u1.w * w1.w
                    + u2.x * w2.x + u2.y * w2.y + u2.z * w2.z + u2.w * w2.w
                    + u3.x * w3.x + u3.y * w3.y + u3.z * w3.z + u3.w * w3.w;
            // |y| <= |u||w| ~ 12 max -> exp safe in f32 without max-subtraction
            float e = active ? __expf(y) : 0.f;
            float Z = e;
            for (int k = 16; k; k >>= 1) Z += __shfl_xor(Z, k);
            float p = e / Z;
            if (mode == 0) {
                acc_sc += p;
            } else {
                a0.x += p * u0.x; a0.y += p * u0.y; a0.z += p * u0.z; a0.w += p * u0.w;
                a1.x += p * u1.x; a1.y += p * u1.y; a1.z += p * u1.z; a1.w += p * u1.w;
                a2.x += p * u2.x; a2.y += p * u2.y; a2.z += p * u2.z; a2.w += p * u2.w;
                a3.x += p * u3.x; a3.y += p * u3.y; a3.z += p * u3.z; a3.w += p * u3.w;
                acc_ent += p * (y - __logf(Z));   // p*log(p), exact 0 for p==0
            }
        }
        __syncthreads();   // LDS reused next step
    }

    if (mode == 0) {
        le[tid] = acc_sc;
        __syncthreads();
        if (tid < 32) {
            float t = 0.f;
            for (int s = 0; s < 8; s++) t += le[s * 32 + tid];
            atomicAdd(&scores[b * J_ + tid], t);
        }
    } else {
        float* ls = (float*)lds;          // reuse staging buffer (8320 floats >= 4096)
        float* myl = ls + tid * 16;
        ((float4*)myl)[0] = a0; ((float4*)myl)[1] = a1;
        ((float4*)myl)[2] = a2; ((float4*)myl)[3] = a3;
        le[tid] = acc_ent;
        __syncthreads();
        for (int idx = tid; idx < 512; idx += 256) {
            int jj = idx >> 4, nn = idx & 15;
            float t = 0.f;
            for (int s = 0; s < 8; s++) t += ls[(s * 32 + jj) * 16 + nn];
            atomicAdd(&s_out[(b * J_ + jj) * N_ + nn], t);
        }
        for (int s = 128; s >= 1; s >>= 1) {
            if (tid < s) le[tid] += le[tid + s];
            __syncthreads();
        }
        if (tid == 0) atomicAdd(&ent[b * 3 + ent_idx], -le[0] * (1.f / (float)I_));
    }
}

// Stable top-K over 32 scores per example (tie-break: lower index, as jax.lax.top_k).
__global__ void topk_kernel(const float* __restrict__ scores, int* __restrict__ mask, int K) {
    int b = blockIdx.x;
    int tid = threadIdx.x;   // 64, first 32 active
    __shared__ float ls[32];
    if (tid < 32) ls[tid] = scores[b * 32 + tid];
    __syncthreads();
    if (tid < 32) {
        float sv = ls[tid];
        int rank = 0;
        for (int jj = 0; jj < 32; jj++) {
            float o = ls[jj];
            rank += (o > sv) || (o == sv && jj < tid);
        }
        mask[b * 32 + tid] = (rank < K) ? 1 : 0;
    }
}

extern "C" void kernel_launch(void* const* d_in, const int* in_sizes, int n_in,
                              void* d_out, int out_size, void* d_ws, size_t ws_size,
                              hipStream_t stream) {
    const float* U    = (const float*)d_in[0];
    const float* bias = (const float*)d_in[1];
    float* ws  = (float*)d_ws;
    float* out = (float*)d_out;
    float* ent = out + B_ * J_ * N_;

    float* w   = ws + OFF_W;
    float* s0  = ws + OFF_S0;
    float* s1  = ws + OFF_S1;
    float* s2  = ws + OFF_S2;
    float* sc0 = ws + OFF_SC0;
    float* sc1 = ws + OFF_SC1;
    int*   m0  = (int*)(ws + OFF_M0);
    int*   m1  = (int*)(ws + OFF_M1);

    zero_kernel<<<544, 256, 0, stream>>>(ws, ent);

    // iter 0: c uniform 1/32   (U traversal: ascending)
    sum_kernel<<<B_ * J_, 256, 0, stream>>>(U, s0);
    vupdate_kernel<<<B_, 512, 0, stream>>>(s0, bias, w, nullptr, ent, 1.f / 32.f, 0);

    // scores for top-20 mask   (descending -> reuse L3 tail of sum pass)
    pass_kernel<<<B_ * NT, 256, 0, stream>>>(U, w, nullptr, sc0, nullptr, nullptr, 0, 0, 1);
    topk_kernel<<<B_, 64, 0, stream>>>(sc0, m0, 20);

    // iter 1: masked softmax -> s1, entropy1; w2 = w1 + v1   (ascending)
    pass_kernel<<<B_ * NT, 256, 0, stream>>>(U, w, m0, nullptr, s1, ent, 1, 1, 0);
    vupdate_kernel<<<B_, 512, 0, stream>>>(s1, bias, w, nullptr, ent, 1.f, 1);

    // scores for top-12 mask   (descending)
    pass_kernel<<<B_ * NT, 256, 0, stream>>>(U, w, m0, sc1, nullptr, nullptr, 0, 0, 1);
    topk_kernel<<<B_, 64, 0, stream>>>(sc1, m1, 12);

    // iter 2: masked softmax -> s2, entropy2; v2 -> output   (ascending)
    pass_kernel<<<B_ * NT, 256, 0, stream>>>(U, w, m1, nullptr, s2, ent, 2, 1, 0);
    vupdate_kernel<<<B_, 512, 0, stream>>>(s2, bias, nullptr, out, ent, 1.f, 2);
}